// Round 5
// baseline (496.139 us; speedup 1.0000x reference)
//
#include <hip/hip_runtime.h>
#include <math.h>

#define NB 128
#define NS 256
#define NH 768
#define NL 24
#define ASTR 68   // A-tile LDS stride (words): 68%32=4 -> 2-way banks, 16B-aligned rows
#define SCLS 28   // scl row stride (words): 16B-aligned rows, col 24 = pad for garbage lanes

// DECOMPOSITION PROBE ROUND: bodies identical to R4, but ner_emis repeats its body
// 8x and ner_viterbi 4x (idempotent recomputation) so each kernel's per-dispatch
// duration exceeds the ~59 us fill cutoff and appears in the rocprof top-5.
#define EMIS_REPS 8
#define VIT_REPS  4

// ---------------- Kernel A: emissions = sigmoid(tf[b,t+1,:] @ W + b) for t < n_b ----
__global__ __launch_bounds__(256) void ner_emis(
    const float* __restrict__ tf, const int* __restrict__ tlm,
    const float* __restrict__ W, const float* __restrict__ bias,
    float* __restrict__ E)
{
    const int b    = blockIdx.x >> 3;
    const int tile = (blockIdx.x & 7) << 5;         // token base of this tile
    const int tid  = threadIdx.x;
    if (tlm[b*NS + tile] == 0) return;              // prefix mask: whole tile invalid

    __shared__ float lds[8*32*25];                  // 25.6 KB union
    float* As = lds;                                // [32][ASTR] = 2176 words (8.5 KB)
    float* Ws = lds + 32*ASTR;                      // [64][24]   = 1536 words (6 KB)
    float* Pr = lds;                                // [8][32][25] reduction (after K-loop)

    const int tok  = tid & 15;
    const int ksub = tid >> 4;                      // 0..15
    const int kk   = ksub << 2;                     // k base within 64-chunk
    const int rot  = ksub & 3;                      // bank-phase rotation

    const float* tfb = tf + (size_t)(b*NS)*NH;

    // A-stage addressing (fixed per thread)
    const int rowA0 = tid >> 4,            c4A0 = tid & 15;
    const int rowA1 = (tid + 256) >> 4,    c4A1 = tid & 15;   // (tid+256)&15 == tid&15
    int trow0 = tile + rowA0 + 1; if (trow0 > 255) trow0 = 255;
    int trow1 = tile + rowA1 + 1; if (trow1 > 255) trow1 = 255;
    const float* srcA0 = tfb + (size_t)trow0*NH + (c4A0 << 2);
    const float* srcA1 = tfb + (size_t)trow1*NH + (c4A1 << 2);

    for (int rep = 0; rep < EMIS_REPS; ++rep) {
        __syncthreads();                            // protect LDS reuse across reps

        float acc0[NL], acc1[NL];
        #pragma unroll
        for (int l = 0; l < NL; ++l) { acc0[l] = 0.f; acc1[l] = 0.f; }

        float4 pa0, pa1, pw0, pw1;
        // ---- prologue: load + commit chunk 0 ----
        pa0 = *(const float4*)(srcA0);
        pa1 = *(const float4*)(srcA1);
        {
            const float4* wsrc = (const float4*)(W);
            pw0 = wsrc[tid];
            if (tid < 128) pw1 = wsrc[tid + 256];
        }
        {
            float* d0 = As + rowA0*ASTR + (c4A0 << 2);
            d0[0]=pa0.x; d0[1]=pa0.y; d0[2]=pa0.z; d0[3]=pa0.w;
            float* d1 = As + rowA1*ASTR + (c4A1 << 2);
            d1[0]=pa1.x; d1[1]=pa1.y; d1[2]=pa1.z; d1[3]=pa1.w;
            ((float4*)Ws)[tid] = pw0;
            if (tid < 128) ((float4*)Ws)[tid + 256] = pw1;
        }
        __syncthreads();

        for (int kc0 = 0; kc0 < NH; kc0 += 64) {
            const bool more = (kc0 + 64 < NH);
            if (more) {   // issue next chunk's loads now; wait lands after compute
                pa0 = *(const float4*)(srcA0 + kc0 + 64);
                pa1 = *(const float4*)(srcA1 + kc0 + 64);
                const float4* wsrc = (const float4*)(W + (size_t)(kc0 + 64)*NL);
                pw0 = wsrc[tid];
                if (tid < 128) pw1 = wsrc[tid + 256];
            }

            const float* A0 = As + tok*ASTR + kk;
            const float* A1 = A0 + 16*ASTR;
            const float* Wr = Ws + kk*NL;
            #pragma unroll
            for (int s = 0; s < 4; ++s) {
                const int j = (s + rot) & 3;        // rotated row order (bank phase)
                float a0 = A0[j];
                float a1 = A1[j];
                const float4* w4 = (const float4*)(Wr + j*NL);
                float wv[NL];
                #pragma unroll
                for (int i = 0; i < 6; ++i) {       // 6 broadcast ds_read_b128
                    float4 w = w4[i];
                    wv[4*i+0] = w.x; wv[4*i+1] = w.y; wv[4*i+2] = w.z; wv[4*i+3] = w.w;
                }
                #pragma unroll
                for (int l = 0; l < NL; ++l) {
                    acc0[l] = fmaf(a0, wv[l], acc0[l]);
                    acc1[l] = fmaf(a1, wv[l], acc1[l]);
                }
            }
            __syncthreads();                        // all reads of this chunk done

            if (more) {                             // commit prefetched chunk to LDS
                float* d0 = As + rowA0*ASTR + (c4A0 << 2);
                d0[0]=pa0.x; d0[1]=pa0.y; d0[2]=pa0.z; d0[3]=pa0.w;
                float* d1 = As + rowA1*ASTR + (c4A1 << 2);
                d1[0]=pa1.x; d1[1]=pa1.y; d1[2]=pa1.z; d1[3]=pa1.w;
                ((float4*)Ws)[tid] = pw0;
                if (tid < 128) ((float4*)Ws)[tid + 256] = pw1;
                __syncthreads();
            }
        }

        // ---- fold 16 ksub partials -> 8 (ksub>=8 publish, ksub<8 add), then final ----
        if (ksub >= 8) {
            float* p = Pr + ((ksub-8)*32 + tok)*25;
            float* q = p + 16*25;
            #pragma unroll
            for (int l = 0; l < NL; ++l) { p[l] = acc0[l]; q[l] = acc1[l]; }
        }
        __syncthreads();
        if (ksub < 8) {
            const float* p = Pr + (ksub*32 + tok)*25;
            const float* q = p + 16*25;
            #pragma unroll
            for (int l = 0; l < NL; ++l) { acc0[l] += p[l]; acc1[l] += q[l]; }
        }
        __syncthreads();
        if (ksub < 8) {
            float* p = Pr + (ksub*32 + tok)*25;
            float* q = p + 16*25;
            #pragma unroll
            for (int l = 0; l < NL; ++l) { p[l] = acc0[l]; q[l] = acc1[l]; }
        }
        __syncthreads();

        const int* tm = tlm + b*NS + tile;
        float* Eb = E + (size_t)(b*NS + tile)*NL;
        #pragma unroll
        for (int i = 0; i < 3; ++i) {
            int o = tid + (i << 8);                 // 0..767 (32 tok x 24 lab)
            int t = o / NL, l = o % NL;
            if (tm[t]) {
                float s = 0.f;
                #pragma unroll
                for (int ks = 0; ks < 8; ++ks)      // fixed ascending order: deterministic
                    s += Pr[(ks*32 + t)*25 + l];
                float x = s + bias[l];
                Eb[t*NL + l] = 1.0f/(1.0f + expf(-x));
            }
        }
    }
}

// ---------------- Kernel B: masked Viterbi decode, one block (256 thr) per batch ----
__global__ __launch_bounds__(256) void ner_viterbi(
    const float* __restrict__ E, const int* __restrict__ tlm,
    const float* __restrict__ trans, const float* __restrict__ st,
    const float* __restrict__ en, int* __restrict__ out)
{
    const int tid = threadIdx.x;
    const int b   = blockIdx.x;
    const int bS  = b*NS;

    __shared__ float Esh[NS*NL];            // preloaded emissions (24 KB)
    __shared__ float scl[NS*SCLS];          // per-step score vectors (28 KB)
    __shared__ float Tt[NL*NL];             // Tt[c*24+p] = T[p][c]
    __shared__ float fin[32];
    __shared__ unsigned char tr_s[NL][NS];  // trace[hypothesis][t]
    __shared__ int chosen[12];
    __shared__ int nsh, ltag;

    {
        const float4* src = (const float4*)(E + (size_t)bS*NL);
        float4* dst = (float4*)Esh;
        #pragma unroll
        for (int j = 0; j < 6; ++j) dst[tid + (j << 8)] = src[tid + (j << 8)];
    }
    for (int i = tid; i < NL*NL; i += 256) {
        int c = i / NL, p = i % NL;
        Tt[i] = trans[p*NL + c];
    }
    if (tid < 64) {   // n = lengths[b]-2 (contiguous prefix mask)
        int a = tlm[bS+tid] + tlm[bS+tid+64] + tlm[bS+tid+128] + tlm[bS+tid+192];
        #pragma unroll
        for (int off = 32; off > 0; off >>= 1) a += __shfl_down(a, off, 64);
        if (tid == 0) nsh = a;
    }
    __syncthreads();
    const int n = nsh;   // n >= 1 always

    for (int rep = 0; rep < VIT_REPS; ++rep) {
        __syncthreads();                     // protect LDS reuse across reps

        // ---- forward: all 64 lanes of wave 0; lanes c and c+32 both own tag c ----
        if (tid < 64) {
            const int lane = tid;
            const int h    = lane >> 5;          // half: prev-tags [12h, 12h+12)
            const int c    = lane & 31;          // tag; c>=24 lanes garbage (never sourced)
            const int cidx = (c < 24) ? c : 23;  // clamped index for global reads
            const int coff = (c < 24) ? c : 24;  // scl column (24 = pad)
            const int p0   = h * 12;

            float Tc[12];
            #pragma unroll
            for (int j = 0; j < 12; ++j) Tc[j] = trans[(p0 + j)*NL + cidx];

            int idxv[12];
            #pragma unroll
            for (int j = 0; j < 12; ++j) idxv[j] = (p0 + j) << 2;

            auto bp = [](int idx4, float v) {   // pull lane (idx4/4)'s v — bit-exact
                return __int_as_float(__builtin_amdgcn_ds_bpermute(idx4, __float_as_int(v)));
            };

            float sv = st[cidx] + Esh[cidx];     // identical in lanes c and c+32
            scl[coff] = sv;                      // t=0 score vector (for backtrack)

            auto step = [&](int t, float em) {
                float cand[12];
                #pragma unroll
                for (int j = 0; j < 12; ++j)     // 12 indep bpermutes
                    cand[j] = bp(idxv[j], sv) + Tc[j];
                float a0 = fmaxf(fmaxf(cand[0], cand[1]),  cand[2]);
                float a1 = fmaxf(fmaxf(cand[3], cand[4]),  cand[5]);
                float a2 = fmaxf(fmaxf(cand[6], cand[7]),  cand[8]);
                float a3 = fmaxf(fmaxf(cand[9], cand[10]), cand[11]);
                float pm = fmaxf(fmaxf(a0, a1), fmaxf(a2, a3));   // partial over 12 prevs
#if __has_builtin(__builtin_amdgcn_permlane32_swap)
                auto r = __builtin_amdgcn_permlane32_swap(
                             __float_as_int(pm), __float_as_int(pm), false, false);
                float best = fmaxf(__int_as_float(r[0]), __int_as_float(r[1]));
#else
                float best = fmaxf(pm, bp((lane ^ 32) << 2, pm));
#endif
                sv = best + em;
                scl[t*SCLS + coff] = sv;         // off critical path (backtrack input)
            };

            int t = 1;
            for (; t + 8 <= n; t += 8) {
                float em[8];
                const float* eb = Esh + t*NL + cidx;
                #pragma unroll
                for (int j = 0; j < 8; ++j) em[j] = eb[j*NL];   // 8 indep ds_read
                #pragma unroll
                for (int j = 0; j < 8; ++j) step(t + j, em[j]);
            }
            for (; t < n; ++t) step(t, Esh[t*NL + cidx]);
            fin[c] = sv + en[cidx];              // c>=24 -> pad slots of fin[32]
        }
        __syncthreads();

        if (tid == 0) {   // argmax(final), first-max tie rule like jnp.argmax
            float bv = fin[0]; int bt = 0;
            #pragma unroll
            for (int cc = 1; cc < 24; ++cc) { if (fin[cc] > bv) { bv = fin[cc]; bt = cc; } }
            ltag = bt;
        }
        __syncthreads();

        // ---- backtrack: 10 windows x 24 hypotheses, recompute backpointers ----
        const int K = (n > 1) ? (n - 1 + 9) / 10 : 1;
        if (n > 1 && tid < 240) {
            const int w = tid / 24 + 1, h = tid % 24;
            int tlo = (w-1)*K; if (tlo > n-1) tlo = n-1;
            int thi = w*K;     if (thi > n-1) thi = n-1;
            int cur = h;
            for (int t = thi; t > tlo; --t) {
                const float4* sp = (const float4*)(scl + (t-1)*SCLS);
                const float4* up = (const float4*)(Tt  + cur*NL);
                float cand[24];
                #pragma unroll
                for (int i = 0; i < 6; ++i) {
                    float4 s = sp[i], u = up[i];
                    cand[4*i+0] = s.x + u.x;     // bitwise-identical to forward cand
                    cand[4*i+1] = s.y + u.y;
                    cand[4*i+2] = s.z + u.z;
                    cand[4*i+3] = s.w + u.w;
                }
                float best = cand[0]; int arg = 0;
                #pragma unroll
                for (int p = 1; p < 24; ++p) { if (cand[p] > best) { best = cand[p]; arg = p; } }
                tr_s[h][t-1] = (unsigned char)arg;
                cur = arg;
            }
        }
        __syncthreads();

        if (tid == 0) {   // stitch windows
            int cur = ltag;
            for (int w = 10; w >= 1; --w) {
                chosen[w] = cur;
                int tlo = (w-1)*K; if (tlo > n-1) tlo = n-1;
                int thi = w*K;     if (thi > n-1) thi = n-1;
                if (thi > tlo) cur = tr_s[cur][tlo];
            }
        }
        __syncthreads();

        {   // emit path: t >= n-1 -> last_tag (identity backpointers on padding)
            const int t = tid;
            int tag;
            if (t >= n-1) tag = ltag;
            else { int w = t / K + 1; tag = tr_s[chosen[w]][t]; }
            out[bS + t] = tag;
        }
    }
}

extern "C" void kernel_launch(void* const* d_in, const int* in_sizes, int n_in,
                              void* d_out, int out_size, void* d_ws, size_t ws_size,
                              hipStream_t stream) {
    const float* tf    = (const float*)d_in[0];
    const int*   tlm   = (const int*)  d_in[2];   // true_label_mask
    const float* W     = (const float*)d_in[3];
    const float* bias  = (const float*)d_in[4];
    const float* trans = (const float*)d_in[5];
    const float* st    = (const float*)d_in[6];
    const float* en    = (const float*)d_in[7];
    float* E = (float*)d_ws;                      // [128,256,24] fp32 = 3.1 MB

    ner_emis<<<dim3(NB*8), dim3(256), 0, stream>>>(tf, tlm, W, bias, E);
    ner_viterbi<<<dim3(NB), dim3(256), 0, stream>>>(E, tlm, trans, st, en, (int*)d_out);
}

// Round 6
// 297.971 us; speedup vs baseline: 1.6651x; 1.6651x over previous
//
#include <hip/hip_runtime.h>
#include <math.h>

#define NB 128
#define NS 256
#define NH 768
#define NL 24
#define SCLS 28   // scl row stride (words): 112B rows, 16B-aligned; col 24+ = pad

// ---------------- Kernel A: emissions = sigmoid(tf[b,t+1,:] @ W + b) for t < n_b ----
// DS-pipe-free rewrite (R5 probe: old version was LDS-broadcast-bound at ~2760
// cyc/chunk). 64-token tiles; 4 waves split K (192 k each); lane = token, so A rows
// stream as per-lane global float4 (64B-line temporal reuse, no LDS staging, no
// barriers in the K loop). W addresses are wave-uniform (k uniform per wave via
// readfirstlane) -> scalar-cache path. LDS only for the final 4-partial reduction.
__global__ __launch_bounds__(256) void ner_emis(
    const float* __restrict__ tf, const int* __restrict__ tlm,
    const float* __restrict__ W, const float* __restrict__ bias,
    float* __restrict__ E)
{
    const int b    = blockIdx.x >> 2;
    const int tile = (blockIdx.x & 3) << 6;         // token base (64-token tile)
    const int tid  = threadIdx.x;
    if (tlm[b*NS + tile] == 0) return;              // prefix mask: whole tile invalid

    __shared__ float Pr[4*64*25];                   // [wave][tok][25] partials, 25.6 KB

    const int lane = tid & 63;                      // token within tile
    const int w    = __builtin_amdgcn_readfirstlane(tid >> 6);  // uniform wave id
    const int ks   = w * 192;                       // this wave's k range

    int trow = tile + lane + 1;                     // feature row = token+1
    if (trow > 255) trow = 255;                     // clamp (row invalid anyway)
    const float* srcA = tf + ((size_t)b*NS + trow)*NH + ks;

    float acc[NL];
    #pragma unroll
    for (int l = 0; l < NL; ++l) acc[l] = 0.f;

    auto fma24 = [&](float av, const float* wr) {
        #pragma unroll
        for (int l = 0; l < NL; ++l) acc[l] = fmaf(av, wr[l], acc[l]);
    };

    // 12 groups of 16 k (one 64B line per lane per group), 1-group prefetch
    float4 c0 = *(const float4*)(srcA);
    float4 c1 = *(const float4*)(srcA + 4);
    float4 c2 = *(const float4*)(srcA + 8);
    float4 c3 = *(const float4*)(srcA + 12);

    for (int kg = 0; kg < 12; ++kg) {
        float4 n0, n1, n2, n3;
        const bool more = (kg < 11);
        if (more) {
            const float* ns = srcA + ((kg + 1) << 4);
            n0 = *(const float4*)(ns);
            n1 = *(const float4*)(ns + 4);
            n2 = *(const float4*)(ns + 8);
            n3 = *(const float4*)(ns + 12);
        }
        const float* wk = W + (size_t)(ks + (kg << 4))*NL;   // uniform address
        fma24(c0.x, wk);          fma24(c0.y, wk + NL);
        fma24(c0.z, wk + 2*NL);   fma24(c0.w, wk + 3*NL);
        fma24(c1.x, wk + 4*NL);   fma24(c1.y, wk + 5*NL);
        fma24(c1.z, wk + 6*NL);   fma24(c1.w, wk + 7*NL);
        fma24(c2.x, wk + 8*NL);   fma24(c2.y, wk + 9*NL);
        fma24(c2.z, wk + 10*NL);  fma24(c2.w, wk + 11*NL);
        fma24(c3.x, wk + 12*NL);  fma24(c3.y, wk + 13*NL);
        fma24(c3.z, wk + 14*NL);  fma24(c3.w, wk + 15*NL);
        if (more) { c0 = n0; c1 = n1; c2 = n2; c3 = n3; }
    }

    // ---- reduce 4 wave-partials in fixed order, sigmoid, masked store ----
    {
        float* p = Pr + ((w << 6) + lane)*25;
        #pragma unroll
        for (int l = 0; l < NL; ++l) p[l] = acc[l];
    }
    __syncthreads();

    const int* tm = tlm + b*NS + tile;
    float* Eb = E + (size_t)(b*NS + tile)*NL;
    #pragma unroll
    for (int i = 0; i < 6; ++i) {
        int o = tid + (i << 8);                     // 0..1535 (64 tok x 24 lab)
        int t = o / NL, l = o - t*NL;
        if (tm[t]) {
            float s = ((Pr[t*25 + l] + Pr[(64 + t)*25 + l])
                       + Pr[(128 + t)*25 + l]) + Pr[(192 + t)*25 + l];
            float x = s + bias[l];
            Eb[o] = 1.0f/(1.0f + expf(-x));
        }
    }
}

// ---------------- Kernel B: masked Viterbi decode, one block (256 thr) per batch ----
// DPP-first forward step (see round notes): phase A = own 16-row via row_ror:1..15
// (VALU, no memory latency); phase B = other row via one ds_bpermute(lane^16) hidden
// under phase A + the same rotations. T-constants self-calibrated by applying the
// actual DPP instruction to laneid at setup. scl values bitwise identical to R4.
__global__ __launch_bounds__(256) void ner_viterbi(
    const float* __restrict__ E, const int* __restrict__ tlm,
    const float* __restrict__ trans, const float* __restrict__ st,
    const float* __restrict__ en, int* __restrict__ out)
{
    const int tid = threadIdx.x;
    const int b   = blockIdx.x;
    const int bS  = b*NS;

    __shared__ float Esh[NS*NL];            // preloaded emissions (24 KB)
    __shared__ float scl[NS*SCLS];          // per-step score vectors (28 KB)
    __shared__ float Tt[NL*NL];             // Tt[c*24+p] = T[p][c]
    __shared__ float fin[32];
    __shared__ unsigned char tr_s[NL][NS];  // trace[hypothesis][t]
    __shared__ int chosen[12];
    __shared__ int nsh, ltag;

    {
        const float4* src = (const float4*)(E + (size_t)bS*NL);
        float4* dst = (float4*)Esh;
        #pragma unroll
        for (int j = 0; j < 6; ++j) dst[tid + (j << 8)] = src[tid + (j << 8)];
    }
    for (int i = tid; i < NL*NL; i += 256) {
        int c = i / NL, p = i % NL;
        Tt[i] = trans[p*NL + c];
    }
    if (tid < 64) {   // n = lengths[b]-2 (contiguous prefix mask)
        int a = tlm[bS+tid] + tlm[bS+tid+64] + tlm[bS+tid+128] + tlm[bS+tid+192];
        #pragma unroll
        for (int off = 32; off > 0; off >>= 1) a += __shfl_down(a, off, 64);
        if (tid == 0) nsh = a;
    }
    __syncthreads();
    const int n = nsh;   // n >= 1 always

    if (tid < 64) {
        const int lane = tid;
        const int c    = lane & 31;          // tag; c>=24 are pads (T=-1e30, never win)
        const int cidx = (c < 24) ? c : 23;  // clamped index for em/trans reads
        const int coff = (c < 24) ? c : 24;  // scl column (24 = pad)
        const int swIdx = (lane ^ 16) << 2;  // bpermute byte index: other 16-row

        float TA[16], TB[16];
        {   // r = 0: identity
            int aP = c;
            int bP = (lane ^ 16) & 31;
            TA[0] = (c < 24 && aP < 24) ? trans[aP*NL + cidx] : -1e30f;
            TB[0] = (c < 24 && bP < 24) ? trans[bP*NL + cidx] : -1e30f;
        }
        #define CAL(r) { \
            int srcl = __builtin_amdgcn_update_dpp(lane, lane, (0x120 + r), 0xF, 0xF, false); \
            int aP = srcl & 31; int bP = (srcl ^ 16) & 31; \
            TA[r] = (c < 24 && aP < 24) ? trans[aP*NL + cidx] : -1e30f; \
            TB[r] = (c < 24 && bP < 24) ? trans[bP*NL + cidx] : -1e30f; }
        CAL(1)  CAL(2)  CAL(3)  CAL(4)  CAL(5)  CAL(6)  CAL(7)
        CAL(8)  CAL(9)  CAL(10) CAL(11) CAL(12) CAL(13) CAL(14) CAL(15)
        #undef CAL

        float sv = st[cidx] + Esh[cidx];
        scl[coff] = sv;                      // t=0 score vector (for backtrack)

        #define F3(x,y,z) fmaxf(fmaxf(x,y),z)

        auto step = [&](int t, float em) {
            int svi = __float_as_int(sv);
            int swi = __builtin_amdgcn_ds_bpermute(swIdx, svi);  // issue early
            float aa0 = sv + TA[0];
            #define CA(r) float aa##r = __int_as_float(__builtin_amdgcn_update_dpp( \
                svi, svi, (0x120 + r), 0xF, 0xF, false)) + TA[r];
            CA(1)  CA(2)  CA(3)  CA(4)  CA(5)  CA(6)  CA(7)
            CA(8)  CA(9)  CA(10) CA(11) CA(12) CA(13) CA(14) CA(15)
            #undef CA
            float mA = fmaxf(fmaxf(F3(aa0,aa1,aa2),  F3(aa3,aa4,aa5)),
                       fmaxf(F3(aa6,aa7,aa8),
                       fmaxf(F3(aa9,aa10,aa11), fmaxf(F3(aa12,aa13,aa14), aa15))));
            float sswap = __int_as_float(swi);
            float bb0 = sswap + TB[0];
            #define CB(r) float bb##r = __int_as_float(__builtin_amdgcn_update_dpp( \
                swi, swi, (0x120 + r), 0xF, 0xF, false)) + TB[r];
            CB(1)  CB(2)  CB(3)  CB(4)  CB(5)  CB(6)  CB(7)
            CB(8)  CB(9)  CB(10) CB(11) CB(12) CB(13) CB(14) CB(15)
            #undef CB
            float mB = fmaxf(fmaxf(F3(bb0,bb1,bb2),  F3(bb3,bb4,bb5)),
                       fmaxf(F3(bb6,bb7,bb8),
                       fmaxf(F3(bb9,bb10,bb11), fmaxf(F3(bb12,bb13,bb14), bb15))));
            sv = fmaxf(mA, mB) + em;
            scl[t*SCLS + coff] = sv;         // off critical path (backtrack input)
        };

        int t = 1;
        for (; t + 8 <= n; t += 8) {
            float em[8];
            const float* eb = Esh + t*NL + cidx;
            #pragma unroll
            for (int j = 0; j < 8; ++j) em[j] = eb[j*NL];   // 8 indep ds_read, imm offs
            #pragma unroll
            for (int j = 0; j < 8; ++j) step(t + j, em[j]);
        }
        for (; t < n; ++t) step(t, Esh[t*NL + cidx]);
        fin[c] = sv + en[cidx];              // lanes 32-63 duplicate-write same values
    }
    __syncthreads();

    if (tid == 0) {   // argmax(final), first-max tie rule like jnp.argmax
        float bv = fin[0]; int bt = 0;
        #pragma unroll
        for (int cc = 1; cc < 24; ++cc) { if (fin[cc] > bv) { bv = fin[cc]; bt = cc; } }
        ltag = bt;
    }
    __syncthreads();

    // ---- backtrack: 10 windows x 24 hypotheses, recompute backpointers ----
    const int K = (n > 1) ? (n - 1 + 9) / 10 : 1;
    if (n > 1 && tid < 240) {
        const int w = tid / 24 + 1, h = tid % 24;
        int tlo = (w-1)*K; if (tlo > n-1) tlo = n-1;
        int thi = w*K;     if (thi > n-1) thi = n-1;
        int cur = h;
        for (int t = thi; t > tlo; --t) {
            const float4* sp = (const float4*)(scl + (t-1)*SCLS);
            const float4* up = (const float4*)(Tt  + cur*NL);
            float cand[24];
            #pragma unroll
            for (int i = 0; i < 6; ++i) {
                float4 s = sp[i], u = up[i];
                cand[4*i+0] = s.x + u.x;     // bitwise-identical to forward cand
                cand[4*i+1] = s.y + u.y;
                cand[4*i+2] = s.z + u.z;
                cand[4*i+3] = s.w + u.w;
            }
            float best = cand[0]; int arg = 0;
            #pragma unroll
            for (int p = 1; p < 24; ++p) { if (cand[p] > best) { best = cand[p]; arg = p; } }
            tr_s[h][t-1] = (unsigned char)arg;
            cur = arg;
        }
    }
    __syncthreads();

    if (tid == 0) {   // stitch windows
        int cur = ltag;
        for (int w = 10; w >= 1; --w) {
            chosen[w] = cur;
            int tlo = (w-1)*K; if (tlo > n-1) tlo = n-1;
            int thi = w*K;     if (thi > n-1) thi = n-1;
            if (thi > tlo) cur = tr_s[cur][tlo];
        }
    }
    __syncthreads();

    {   // emit path: t >= n-1 -> last_tag (identity backpointers on padding)
        const int t = tid;
        int tag;
        if (t >= n-1) tag = ltag;
        else { int w = t / K + 1; tag = tr_s[chosen[w]][t]; }
        out[bS + t] = tag;
    }
}

extern "C" void kernel_launch(void* const* d_in, const int* in_sizes, int n_in,
                              void* d_out, int out_size, void* d_ws, size_t ws_size,
                              hipStream_t stream) {
    const float* tf    = (const float*)d_in[0];
    const int*   tlm   = (const int*)  d_in[2];   // true_label_mask
    const float* W     = (const float*)d_in[3];
    const float* bias  = (const float*)d_in[4];
    const float* trans = (const float*)d_in[5];
    const float* st    = (const float*)d_in[6];
    const float* en    = (const float*)d_in[7];
    float* E = (float*)d_ws;                      // [128,256,24] fp32 = 3.1 MB

    ner_emis<<<dim3(NB*4), dim3(256), 0, stream>>>(tf, tlm, W, bias, E);
    ner_viterbi<<<dim3(NB), dim3(256), 0, stream>>>(E, tlm, trans, st, en, (int*)d_out);
}